// Round 1
// baseline (25359.883 us; speedup 1.0000x reference)
//
#include <hip/hip_runtime.h>
#include <hip/hip_bf16.h>
#include <stdint.h>

// 2-layer LSTM, B=512 T=256 I=128 H=512.  Design (round 1):
//  - bf16 convert kernels (x transposed to [T,B,I], weights)
//  - gx = A@W_ih^T + (b_ih+b_hh) via 128x128x64 MFMA GEMM (reg-staged LDS, XOR swizzle,
//    bijective XCD swizzle), gx stored fp32 in ws (bf16 fallback if ws small)
//  - persistent scan kernel per layer: 256 blocks = 8 batch-tiles x 32 h-col slices,
//    1 block/CU forced via 128KB LDS (co-residency), per-step producer/consumer flag
//    sync with agent-scope atomics + acquire/release fences. W_hh slice + h tile in
//    swizzled LDS, MFMA 16x16x32 bf16, c-state fp32 in VGPRs, gates fp32 (v_exp/v_rcp).

#define B_ 512
#define T_ 256
#define I_ 128
#define H_ 512
#define G_ 2048  // 4H

typedef __attribute__((ext_vector_type(8))) short short8;
typedef __attribute__((ext_vector_type(4))) float f32x4;
typedef unsigned short u16;
typedef unsigned int u32;

__device__ inline u16 f2b(float f) {
  union { __hip_bfloat16 h; u16 u; } cv;
  cv.h = __float2bfloat16(f);
  return cv.u;
}
__device__ inline float b2f(u16 u) {
  union { __hip_bfloat16 h; u16 u; } cv;
  cv.u = u;
  return __bfloat162float(cv.h);
}
__device__ inline float sigm(float x) {
  return __builtin_amdgcn_rcpf(1.0f + __builtin_amdgcn_exp2f(-1.4426950408889634f * x));
}
__device__ inline float tanh_(float x) {
  return 1.0f - 2.0f * __builtin_amdgcn_rcpf(__builtin_amdgcn_exp2f(2.8853900817779268f * x) + 1.0f);
}

// x [B,T,I] f32 -> xbt [T,B,I] bf16 (transpose at row level; both sides coalesced)
__global__ __launch_bounds__(256) void k_xcvt(const float* __restrict__ x, u16* __restrict__ xbt) {
  int i = blockIdx.x * 256 + threadIdx.x;  // over T*B*I/4
  int d4 = i & (I_ / 4 - 1);
  int rb = i >> 5;            // t*B + b
  int b = rb & (B_ - 1);
  int t = rb >> 9;
  const float4 v = *(const float4*)(x + ((size_t)b * T_ + t) * I_ + d4 * 4);
  ushort4 o = make_ushort4(f2b(v.x), f2b(v.y), f2b(v.z), f2b(v.w));
  *(ushort4*)(xbt + (size_t)rb * I_ + d4 * 4) = o;
}

__global__ __launch_bounds__(256) void k_cvt_bf16(const float* __restrict__ in, u16* __restrict__ out, int n4) {
  int i = blockIdx.x * 256 + threadIdx.x;
  if (i >= n4) return;
  const float4 v = *(const float4*)(in + (size_t)i * 4);
  ushort4 o = make_ushort4(f2b(v.x), f2b(v.y), f2b(v.z), f2b(v.w));
  *(ushort4*)(out + (size_t)i * 4) = o;
}

// C[M,2048] = A[M,K] @ Bw[2048,K]^T + (bias_a+bias_b); M = T*B = 131072 rows (t-major).
template <int KDIM, bool GX32>
__global__ __launch_bounds__(256) void k_gemm(const u16* __restrict__ A,
                                              const u16* __restrict__ Bw,
                                              const float* __restrict__ bias_a,
                                              const float* __restrict__ bias_b,
                                              void* __restrict__ C) {
  __shared__ u16 lA[128 * 64];
  __shared__ u16 lB[128 * 64];
  const int nwg = gridDim.x;               // divisible by 8
  const int per = nwg >> 3;
  const int wg = blockIdx.x;
  const int swz = (wg & 7) * per + (wg >> 3);  // XCD-contiguous chunks
  const int bn = swz & 15;                  // 16 N tiles of 128
  const int bm = swz >> 4;
  const size_t m0 = (size_t)bm * 128;
  const int n0 = bn * 128;
  const int tid = threadIdx.x;
  const int lane = tid & 63;
  const int wid = tid >> 6;
  const int wm = (wid >> 1) * 64;
  const int wn = (wid & 1) * 64;
  const int l15 = lane & 15;
  const int lq = lane >> 4;

  f32x4 acc[4][4] = {};

  for (int k0 = 0; k0 < KDIM; k0 += 64) {
    __syncthreads();
#pragma unroll
    for (int it = 0; it < 4; ++it) {
      int c = it * 256 + tid;
      int r = c >> 3, s = c & 7;
      int ss = s ^ (r & 7);
      *(float4*)&lA[(r * 8 + ss) * 8] = *(const float4*)&A[(m0 + r) * KDIM + k0 + s * 8];
      *(float4*)&lB[(r * 8 + ss) * 8] = *(const float4*)&Bw[(size_t)(n0 + r) * KDIM + k0 + s * 8];
    }
    __syncthreads();
#pragma unroll
    for (int kk = 0; kk < 2; ++kk) {
      short8 af[4], bfm[4];
#pragma unroll
      for (int mi = 0; mi < 4; ++mi) {
        int r = wm + mi * 16 + l15;
        int s = kk * 4 + lq;
        af[mi] = *(const short8*)&lA[(r * 8 + (s ^ (r & 7))) * 8];
      }
#pragma unroll
      for (int ni = 0; ni < 4; ++ni) {
        int r = wn + ni * 16 + l15;
        int s = kk * 4 + lq;
        bfm[ni] = *(const short8*)&lB[(r * 8 + (s ^ (r & 7))) * 8];
      }
#pragma unroll
      for (int mi = 0; mi < 4; ++mi)
#pragma unroll
        for (int ni = 0; ni < 4; ++ni)
          acc[mi][ni] = __builtin_amdgcn_mfma_f32_16x16x32_bf16(af[mi], bfm[ni], acc[mi][ni], 0, 0, 0);
    }
  }

#pragma unroll
  for (int ni = 0; ni < 4; ++ni) {
    int col = n0 + wn + ni * 16 + l15;
    float bs = bias_a[col] + bias_b[col];
#pragma unroll
    for (int mi = 0; mi < 4; ++mi) {
#pragma unroll
      for (int r = 0; r < 4; ++r) {
        size_t row = m0 + wm + mi * 16 + lq * 4 + r;
        float v = acc[mi][ni][r] + bs;
        if (GX32) ((float*)C)[row * G_ + col] = v;
        else ((u16*)C)[row * G_ + col] = f2b(v);
      }
    }
  }
}

// Persistent scan. Grid = 256 blocks (Bi = blk&7 batch tile of 64 rows, j = blk>>3 slice of
// 16 h-cols -> 64 gate rows). 128KB dynamic LDS forces 1 block/CU => all blocks co-resident.
template <bool GX32, bool WRITE_OUT>
__global__ __launch_bounds__(256, 1) void k_scan(const void* __restrict__ gx,   // [T,B,2048]
                                                 const u16* __restrict__ Whh,   // [2048,512] bf16
                                                 u16* __restrict__ hbuf,        // history or ring, bf16
                                                 float* __restrict__ fpout,     // d_out [B,T,H] (layer1)
                                                 u32* __restrict__ flags,       // [T][8]
                                                 int ring) {
  extern __shared__ u16 smem[];
  u16* lW = smem;             // [64][512] swizzled
  u16* lH = smem + 64 * 512;  // [64][512] swizzled

  const int blk = blockIdx.x;
  const int Bi = blk & 7;
  const int j = blk >> 3;
  const int tid = threadIdx.x;
  const int lane = tid & 63;
  const int wid = tid >> 6;
  const int l15 = lane & 15;
  const int lq = lane >> 4;

  // Stage W_hh slice once: local row r = g*16+i  <->  global gate row g*512 + j*16 + i
  for (int c = tid; c < 64 * 64; c += 256) {
    int r = c >> 6, s = c & 63;
    int gr = (r >> 4) * 512 + j * 16 + (r & 15);
    *(float4*)&lW[r * 512 + (s ^ (r & 7)) * 8] = *(const float4*)&Whh[(size_t)gr * H_ + s * 8];
  }
  __syncthreads();

  const int brow0 = Bi * 64 + wid * 16 + lq * 4;  // + r
  const int colj = j * 16 + l15;
  float cst[4] = {0.f, 0.f, 0.f, 0.f};

  for (int t = 0; t < T_; ++t) {
    // issue gx loads early; they complete under the spin-wait
    float gxv[4][4];
    if (GX32) {
      const float* gp = (const float*)gx + ((size_t)t * B_ + brow0) * G_ + colj;
#pragma unroll
      for (int g = 0; g < 4; ++g)
#pragma unroll
        for (int r = 0; r < 4; ++r) gxv[g][r] = gp[(size_t)r * G_ + g * H_];
    } else {
      const u16* gp = (const u16*)gx + ((size_t)t * B_ + brow0) * G_ + colj;
#pragma unroll
      for (int g = 0; g < 4; ++g)
#pragma unroll
        for (int r = 0; r < 4; ++r) gxv[g][r] = b2f(gp[(size_t)r * G_ + g * H_]);
    }

    f32x4 acc[4] = {};

    if (t > 0) {
      if (tid == 0) {
        const u32* f = &flags[(t - 1) * 8 + Bi];
        u32 guard = 0;
        while (__hip_atomic_load(f, __ATOMIC_ACQUIRE, __HIP_MEMORY_SCOPE_AGENT) < 32u &&
               ++guard < (1u << 24)) {
        }
      }
      __syncthreads();
      __builtin_amdgcn_fence(__ATOMIC_ACQUIRE, "agent");
      // stage h[t-1] rows [Bi*64, Bi*64+64)
      const int slot = ring ? ((t - 1) & 1) : (t - 1);
      const u16* hs = hbuf + (size_t)slot * B_ * H_ + (size_t)Bi * 64 * H_;
      for (int c = tid; c < 64 * 64; c += 256) {
        int r = c >> 6, s = c & 63;
        *(float4*)&lH[r * 512 + (s ^ (r & 7)) * 8] = *(const float4*)&hs[(size_t)r * H_ + s * 8];
      }
      __syncthreads();
#pragma unroll
      for (int kk = 0; kk < 16; ++kk) {
        int s = kk * 4 + lq;
        int ar = wid * 16 + l15;
        short8 af = *(const short8*)&lH[ar * 512 + (s ^ (ar & 7)) * 8];
#pragma unroll
        for (int g = 0; g < 4; ++g) {
          int br = g * 16 + l15;
          short8 bw = *(const short8*)&lW[br * 512 + (s ^ (br & 7)) * 8];
          acc[g] = __builtin_amdgcn_mfma_f32_16x16x32_bf16(af, bw, acc[g], 0, 0, 0);
        }
      }
    }

    const int slot_w = ring ? (t & 1) : t;
    u16* hw = hbuf + (size_t)slot_w * B_ * H_;
#pragma unroll
    for (int r = 0; r < 4; ++r) {
      float gi = sigm(acc[0][r] + gxv[0][r]);
      float gf = sigm(acc[1][r] + gxv[1][r]);
      float gg = tanh_(acc[2][r] + gxv[2][r]);
      float go = sigm(acc[3][r] + gxv[3][r]);
      float cn = gf * cst[r] + gi * gg;
      cst[r] = cn;
      float hn = go * tanh_(cn);
      int row = brow0 + r;
      hw[(size_t)row * H_ + colj] = f2b(hn);
      if (WRITE_OUT) fpout[((size_t)row * T_ + t) * H_ + colj] = hn;
    }
    __threadfence();
    __syncthreads();
    if (tid == 0)
      __hip_atomic_fetch_add(&flags[t * 8 + Bi], 1u, __ATOMIC_RELEASE, __HIP_MEMORY_SCOPE_AGENT);
  }
}

extern "C" void kernel_launch(void* const* d_in, const int* in_sizes, int n_in,
                              void* d_out, int out_size, void* d_ws, size_t ws_size,
                              hipStream_t stream) {
  if (n_in < 9) return;
  const float* x    = (const float*)d_in[0];
  const float* Wih0 = (const float*)d_in[1];
  const float* Whh0 = (const float*)d_in[2];
  const float* bih0 = (const float*)d_in[3];
  const float* bhh0 = (const float*)d_in[4];
  const float* Wih1 = (const float*)d_in[5];
  const float* Whh1 = (const float*)d_in[6];
  const float* bih1 = (const float*)d_in[7];
  const float* bhh1 = (const float*)d_in[8];
  float* out = (float*)d_out;

  const size_t SZ_GX32 = (size_t)T_ * B_ * G_ * 4;
  const size_t SZ_GX16 = (size_t)T_ * B_ * G_ * 2;
  const size_t SZ_XBT  = (size_t)T_ * B_ * I_ * 2;
  const size_t SZ_HB1  = (size_t)T_ * B_ * H_ * 2;
  const size_t SZ_RING = (size_t)2 * B_ * H_ * 2;
  const size_t SZ_WIH0 = (size_t)G_ * I_ * 2;
  const size_t SZ_WHH  = (size_t)G_ * H_ * 2;
  const size_t SZ_FLAGS = (size_t)2 * T_ * 8 * sizeof(u32);
  const size_t others = SZ_XBT + SZ_HB1 + SZ_RING + SZ_WIH0 + 3 * SZ_WHH + SZ_FLAGS + 4096;

  bool gx32 = ws_size >= SZ_GX32 + others;
  if (!gx32 && ws_size < SZ_GX16 + others) return;  // ws too small: fail loudly (no launch)

  uint8_t* p = (uint8_t*)d_ws;
  void* gx   = (void*)p;   p += gx32 ? SZ_GX32 : SZ_GX16;
  u16* xbt   = (u16*)p;    p += SZ_XBT;
  u16* hb1   = (u16*)p;    p += SZ_HB1;
  u16* ring  = (u16*)p;    p += SZ_RING;
  u16* wih0b = (u16*)p;    p += SZ_WIH0;
  u16* whh0b = (u16*)p;    p += SZ_WHH;
  u16* wih1b = (u16*)p;    p += SZ_WHH;
  u16* whh1b = (u16*)p;    p += SZ_WHH;
  u32* flags  = (u32*)p;
  u32* flags0 = flags;
  u32* flags1 = flags + T_ * 8;

  k_xcvt<<<(T_ * B_ * I_ / 4) / 256, 256, 0, stream>>>(x, xbt);
  k_cvt_bf16<<<(G_ * I_ / 4) / 256, 256, 0, stream>>>(Wih0, wih0b, G_ * I_ / 4);
  k_cvt_bf16<<<(G_ * H_ / 4) / 256, 256, 0, stream>>>(Whh0, whh0b, G_ * H_ / 4);
  k_cvt_bf16<<<(G_ * H_ / 4) / 256, 256, 0, stream>>>(Wih1, wih1b, G_ * H_ / 4);
  k_cvt_bf16<<<(G_ * H_ / 4) / 256, 256, 0, stream>>>(Whh1, whh1b, G_ * H_ / 4);
  hipMemsetAsync(flags, 0, SZ_FLAGS, stream);

  const int gemm_grid = (T_ * B_ / 128) * (G_ / 128);  // 16384
  const int SH = 64 * 512 * 2 * 2;                     // 131072 B dynamic LDS

  if (gx32) {
    hipFuncSetAttribute((const void*)&k_scan<true, false>, hipFuncAttributeMaxDynamicSharedMemorySize, SH);
    hipFuncSetAttribute((const void*)&k_scan<true, true>, hipFuncAttributeMaxDynamicSharedMemorySize, SH);
    k_gemm<I_, true><<<gemm_grid, 256, 0, stream>>>(xbt, wih0b, bih0, bhh0, gx);
    k_scan<true, false><<<256, 256, SH, stream>>>(gx, whh0b, hb1, nullptr, flags0, 0);
    k_gemm<H_, true><<<gemm_grid, 256, 0, stream>>>(hb1, wih1b, bih1, bhh1, gx);
    k_scan<true, true><<<256, 256, SH, stream>>>(gx, whh1b, ring, out, flags1, 1);
  } else {
    hipFuncSetAttribute((const void*)&k_scan<false, false>, hipFuncAttributeMaxDynamicSharedMemorySize, SH);
    hipFuncSetAttribute((const void*)&k_scan<false, true>, hipFuncAttributeMaxDynamicSharedMemorySize, SH);
    k_gemm<I_, false><<<gemm_grid, 256, 0, stream>>>(xbt, wih0b, bih0, bhh0, gx);
    k_scan<false, false><<<256, 256, SH, stream>>>(gx, whh0b, hb1, nullptr, flags0, 0);
    k_gemm<H_, false><<<gemm_grid, 256, 0, stream>>>(hb1, wih1b, bih1, bhh1, gx);
    k_scan<false, true><<<256, 256, SH, stream>>>(gx, whh1b, ring, out, flags1, 1);
  }
}

// Round 4
// 4181.151 us; speedup vs baseline: 6.0653x; 6.0653x over previous
//
#include <hip/hip_runtime.h>
#include <hip/hip_bf16.h>
#include <stdint.h>

// 2-layer LSTM, B=512 T=256 I=128 H=512.  Round 2 design (3rd submit; rounds 2-3 were
// broker acquisition timeouts, never benched):
//  - scans no longer use device fences (round-1: buffer_inv/wbl2 per block per step
//    = 51us/step). Cross-block h exchange now uses per-access sc0/sc1 (LLC = cross-XCD
//    coherence point): write-through h stores + vmcnt drain + per-block flag slot store;
//    consumers poll flag line with agent relaxed atomic loads and read h with sc0/sc1
//    loads directly into MFMA A-fragments (no L2 invalidates anywhere).
//  - h LDS tile dropped (global->VGPR); W_hh slice stays in 64KB swizzled LDS.
//  - gx fp32 in ws (bf16 fallback), GEMMs unchanged from round 1.

#define B_ 512
#define T_ 256
#define I_ 128
#define H_ 512
#define G_ 2048  // 4H

typedef __attribute__((ext_vector_type(8))) short short8;
typedef __attribute__((ext_vector_type(4))) float f32x4;
typedef unsigned short u16;
typedef unsigned int u32;

__device__ inline u16 f2b(float f) {
  union { __hip_bfloat16 h; u16 u; } cv;
  cv.h = __float2bfloat16(f);
  return cv.u;
}
__device__ inline float b2f(u16 u) {
  union { __hip_bfloat16 h; u16 u; } cv;
  cv.u = u;
  return __bfloat162float(cv.h);
}
__device__ inline float sigm(float x) {
  return __builtin_amdgcn_rcpf(1.0f + __builtin_amdgcn_exp2f(-1.4426950408889634f * x));
}
__device__ inline float tanh_(float x) {
  return 1.0f - 2.0f * __builtin_amdgcn_rcpf(__builtin_amdgcn_exp2f(2.8853900817779268f * x) + 1.0f);
}

// ---- coherent (LLC-level) access helpers: per-access sc0 sc1, no cache-wide fences ----
__device__ inline short8 ld_b128_coh(const void* p) {
  f32x4 r;
  asm volatile("global_load_dwordx4 %0, %1, off sc0 sc1" : "=v"(r) : "v"(p) : "memory");
  union { f32x4 f; short8 s; } cv;
  cv.f = r;
  return cv.s;
}
__device__ inline void st_b16_coh(void* p, u32 v) {
  asm volatile("global_store_short %0, %1, off sc0 sc1" ::"v"(p), "v"(v) : "memory");
}
__device__ inline void st_b32_coh(void* p, u32 v) {
  asm volatile("global_store_dword %0, %1, off sc0 sc1" ::"v"(p), "v"(v) : "memory");
}

// x [B,T,I] f32 -> xbt [T,B,I] bf16
__global__ __launch_bounds__(256) void k_xcvt(const float* __restrict__ x, u16* __restrict__ xbt) {
  int i = blockIdx.x * 256 + threadIdx.x;  // over T*B*I/4
  int d4 = i & (I_ / 4 - 1);
  int rb = i >> 5;  // t*B + b
  int b = rb & (B_ - 1);
  int t = rb >> 9;
  const float4 v = *(const float4*)(x + ((size_t)b * T_ + t) * I_ + d4 * 4);
  ushort4 o = make_ushort4(f2b(v.x), f2b(v.y), f2b(v.z), f2b(v.w));
  *(ushort4*)(xbt + (size_t)rb * I_ + d4 * 4) = o;
}

__global__ __launch_bounds__(256) void k_cvt_bf16(const float* __restrict__ in, u16* __restrict__ out, int n4) {
  int i = blockIdx.x * 256 + threadIdx.x;
  if (i >= n4) return;
  const float4 v = *(const float4*)(in + (size_t)i * 4);
  ushort4 o = make_ushort4(f2b(v.x), f2b(v.y), f2b(v.z), f2b(v.w));
  *(ushort4*)(out + (size_t)i * 4) = o;
}

// C[M,2048] = A[M,K] @ Bw[2048,K]^T + (bias_a+bias_b); M = T*B rows (t-major).
template <int KDIM, bool GX32>
__global__ __launch_bounds__(256) void k_gemm(const u16* __restrict__ A,
                                              const u16* __restrict__ Bw,
                                              const float* __restrict__ bias_a,
                                              const float* __restrict__ bias_b,
                                              void* __restrict__ C) {
  __shared__ u16 lA[128 * 64];
  __shared__ u16 lB[128 * 64];
  const int nwg = gridDim.x;
  const int per = nwg >> 3;
  const int wg = blockIdx.x;
  const int swz = (wg & 7) * per + (wg >> 3);
  const int bn = swz & 15;
  const int bm = swz >> 4;
  const size_t m0 = (size_t)bm * 128;
  const int n0 = bn * 128;
  const int tid = threadIdx.x;
  const int lane = tid & 63;
  const int wid = tid >> 6;
  const int wm = (wid >> 1) * 64;
  const int wn = (wid & 1) * 64;
  const int l15 = lane & 15;
  const int lq = lane >> 4;

  f32x4 acc[4][4] = {};

  for (int k0 = 0; k0 < KDIM; k0 += 64) {
    __syncthreads();
#pragma unroll
    for (int it = 0; it < 4; ++it) {
      int c = it * 256 + tid;
      int r = c >> 3, s = c & 7;
      int ss = s ^ (r & 7);
      *(float4*)&lA[(r * 8 + ss) * 8] = *(const float4*)&A[(m0 + r) * KDIM + k0 + s * 8];
      *(float4*)&lB[(r * 8 + ss) * 8] = *(const float4*)&Bw[(size_t)(n0 + r) * KDIM + k0 + s * 8];
    }
    __syncthreads();
#pragma unroll
    for (int kk = 0; kk < 2; ++kk) {
      short8 af[4], bfm[4];
#pragma unroll
      for (int mi = 0; mi < 4; ++mi) {
        int r = wm + mi * 16 + l15;
        int s = kk * 4 + lq;
        af[mi] = *(const short8*)&lA[(r * 8 + (s ^ (r & 7))) * 8];
      }
#pragma unroll
      for (int ni = 0; ni < 4; ++ni) {
        int r = wn + ni * 16 + l15;
        int s = kk * 4 + lq;
        bfm[ni] = *(const short8*)&lB[(r * 8 + (s ^ (r & 7))) * 8];
      }
#pragma unroll
      for (int mi = 0; mi < 4; ++mi)
#pragma unroll
        for (int ni = 0; ni < 4; ++ni)
          acc[mi][ni] = __builtin_amdgcn_mfma_f32_16x16x32_bf16(af[mi], bfm[ni], acc[mi][ni], 0, 0, 0);
    }
  }

#pragma unroll
  for (int ni = 0; ni < 4; ++ni) {
    int col = n0 + wn + ni * 16 + l15;
    float bs = bias_a[col] + bias_b[col];
#pragma unroll
    for (int mi = 0; mi < 4; ++mi) {
#pragma unroll
      for (int r = 0; r < 4; ++r) {
        size_t row = m0 + wm + mi * 16 + lq * 4 + r;
        float v = acc[mi][ni][r] + bs;
        if (GX32) ((float*)C)[row * G_ + col] = v;
        else ((u16*)C)[row * G_ + col] = f2b(v);
      }
    }
  }
}

// Persistent scan. 256 blocks = 8 batch groups (Bi=blk&7, 64 rows) x 32 gate-col slices
// (j=blk>>3, 64 gate rows = 16 h cols). W slice in 64KB swizzled LDS; h exchanged via
// LLC with per-access sc0/sc1; per-block flag slot (monotonic completed-step counter).
template <bool GX32, bool WRITE_OUT>
__global__ __launch_bounds__(256, 1) void k_scan(const void* __restrict__ gx,  // [T,B,2048]
                                                 const u16* __restrict__ Whh,  // [2048,512] bf16
                                                 u16* __restrict__ hbuf,       // history or ring-2, bf16
                                                 float* __restrict__ fpout,    // d_out [B,T,H] (layer1)
                                                 u32* __restrict__ flags,      // [8 groups][32 slots]
                                                 int ring) {
  __shared__ u16 lW[64 * 512];  // 64KB, swizzled

  const int blk = blockIdx.x;
  const int Bi = blk & 7;
  const int j = blk >> 3;
  const int tid = threadIdx.x;
  const int lane = tid & 63;
  const int wid = tid >> 6;
  const int l15 = lane & 15;
  const int lq = lane >> 4;

  // Stage W_hh slice once: local row r = g*16+i  <->  global gate row g*512 + j*16 + i
  for (int c = tid; c < 64 * 64; c += 256) {
    int r = c >> 6, s = c & 63;
    int gr = (r >> 4) * 512 + j * 16 + (r & 15);
    *(float4*)&lW[r * 512 + (s ^ (r & 7)) * 8] = *(const float4*)&Whh[(size_t)gr * H_ + s * 8];
  }
  __syncthreads();

  const int arow = Bi * 64 + wid * 16 + l15;       // this lane's A-fragment h row
  const int brow0 = Bi * 64 + wid * 16 + lq * 4;   // C rows (+r)
  const int colj = j * 16 + l15;
  u32* myflags = flags + Bi * 32;
  const int selfslot = ((lane & 31) == j) ? 1 : 0;
  float cst[4] = {0.f, 0.f, 0.f, 0.f};

  for (int t = 0; t < T_; ++t) {
    // gx loads issued early (plain cached loads; gx is stream-once from HBM/L2)
    float gxv[4][4];
    if (GX32) {
      const float* gp = (const float*)gx + ((size_t)t * B_ + brow0) * G_ + colj;
#pragma unroll
      for (int g = 0; g < 4; ++g)
#pragma unroll
        for (int r = 0; r < 4; ++r) gxv[g][r] = gp[(size_t)r * G_ + g * H_];
    } else {
      const u16* gp = (const u16*)gx + ((size_t)t * B_ + brow0) * G_ + colj;
#pragma unroll
      for (int g = 0; g < 4; ++g)
#pragma unroll
        for (int r = 0; r < 4; ++r) gxv[g][r] = b2f(gp[(size_t)r * G_ + g * H_]);
    }

    f32x4 acc[4] = {};

    if (t > 0) {
      // wait for all 32 producers of this batch group to have finished step t-1
      // (own slot excluded: own h stores were drained before our step-(t-1) barrier)
      u32 guard = 0;
      for (;;) {
        u32 v = __hip_atomic_load(&myflags[lane & 31], __ATOMIC_RELAXED, __HIP_MEMORY_SCOPE_AGENT);
        if (__all(selfslot | (v >= (u32)t))) break;
        if (++guard > (1u << 20)) break;  // bounded: wrong answer instead of hang
      }
      const int slot = ring ? ((t - 1) & 1) : (t - 1);
      const u16* hs = hbuf + (size_t)slot * B_ * H_ + (size_t)arow * H_;
      short8 af[16];
#pragma unroll
      for (int kk = 0; kk < 16; ++kk) af[kk] = ld_b128_coh(hs + (kk * 4 + lq) * 8);
      asm volatile("s_waitcnt vmcnt(0)" ::: "memory");
      __builtin_amdgcn_sched_barrier(0);
#pragma unroll
      for (int kk = 0; kk < 16; ++kk) {
        int s = kk * 4 + lq;
#pragma unroll
        for (int g = 0; g < 4; ++g) {
          int br = g * 16 + l15;
          short8 bw = *(const short8*)&lW[br * 512 + (s ^ (br & 7)) * 8];
          acc[g] = __builtin_amdgcn_mfma_f32_16x16x32_bf16(af[kk], bw, acc[g], 0, 0, 0);
        }
      }
    }

    const int slot_w = ring ? (t & 1) : t;
    u16* hw = hbuf + (size_t)slot_w * B_ * H_;
#pragma unroll
    for (int r = 0; r < 4; ++r) {
      float gi = sigm(acc[0][r] + gxv[0][r]);
      float gf = sigm(acc[1][r] + gxv[1][r]);
      float gg = tanh_(acc[2][r] + gxv[2][r]);
      float go = sigm(acc[3][r] + gxv[3][r]);
      float cn = gf * cst[r] + gi * gg;
      cst[r] = cn;
      float hn = go * tanh_(cn);
      int row = brow0 + r;
      st_b16_coh(&hw[(size_t)row * H_ + colj], (u32)f2b(hn));
      if (WRITE_OUT) fpout[((size_t)row * T_ + t) * H_ + colj] = hn;
    }
    asm volatile("s_waitcnt vmcnt(0)" ::: "memory");  // h stores at LLC
    __syncthreads();                                  // all waves drained
    if (tid == 0) st_b32_coh(&myflags[j], (u32)(t + 1));
  }
}

extern "C" void kernel_launch(void* const* d_in, const int* in_sizes, int n_in,
                              void* d_out, int out_size, void* d_ws, size_t ws_size,
                              hipStream_t stream) {
  if (n_in < 9) return;
  const float* x    = (const float*)d_in[0];
  const float* Wih0 = (const float*)d_in[1];
  const float* Whh0 = (const float*)d_in[2];
  const float* bih0 = (const float*)d_in[3];
  const float* bhh0 = (const float*)d_in[4];
  const float* Wih1 = (const float*)d_in[5];
  const float* Whh1 = (const float*)d_in[6];
  const float* bih1 = (const float*)d_in[7];
  const float* bhh1 = (const float*)d_in[8];
  float* out = (float*)d_out;

  const size_t SZ_GX32 = (size_t)T_ * B_ * G_ * 4;
  const size_t SZ_GX16 = (size_t)T_ * B_ * G_ * 2;
  const size_t SZ_XBT  = (size_t)T_ * B_ * I_ * 2;
  const size_t SZ_HB1  = (size_t)T_ * B_ * H_ * 2;
  const size_t SZ_RING = (size_t)2 * B_ * H_ * 2;
  const size_t SZ_WIH0 = (size_t)G_ * I_ * 2;
  const size_t SZ_WHH  = (size_t)G_ * H_ * 2;
  const size_t SZ_FLAGS = (size_t)2 * 8 * 32 * sizeof(u32);
  const size_t others = SZ_XBT + SZ_HB1 + SZ_RING + SZ_WIH0 + 3 * SZ_WHH + SZ_FLAGS + 4096;

  bool gx32 = ws_size >= SZ_GX32 + others;
  if (!gx32 && ws_size < SZ_GX16 + others) return;  // ws too small: fail loudly

  uint8_t* p = (uint8_t*)d_ws;
  void* gx   = (void*)p;   p += gx32 ? SZ_GX32 : SZ_GX16;
  u16* xbt   = (u16*)p;    p += SZ_XBT;
  u16* hb1   = (u16*)p;    p += SZ_HB1;
  u16* ring  = (u16*)p;    p += SZ_RING;
  u16* wih0b = (u16*)p;    p += SZ_WIH0;
  u16* whh0b = (u16*)p;    p += SZ_WHH;
  u16* wih1b = (u16*)p;    p += SZ_WHH;
  u16* whh1b = (u16*)p;    p += SZ_WHH;
  u32* flags  = (u32*)p;
  u32* flags0 = flags;
  u32* flags1 = flags + 8 * 32;

  k_xcvt<<<(T_ * B_ * I_ / 4) / 256, 256, 0, stream>>>(x, xbt);
  k_cvt_bf16<<<(G_ * I_ / 4) / 256, 256, 0, stream>>>(Wih0, wih0b, G_ * I_ / 4);
  k_cvt_bf16<<<(G_ * H_ / 4) / 256, 256, 0, stream>>>(Whh0, whh0b, G_ * H_ / 4);
  k_cvt_bf16<<<(G_ * H_ / 4) / 256, 256, 0, stream>>>(Whh1, whh1b, G_ * H_ / 4);
  k_cvt_bf16<<<(G_ * H_ / 4) / 256, 256, 0, stream>>>(Wih1, wih1b, G_ * H_ / 4);
  hipMemsetAsync(flags, 0, SZ_FLAGS, stream);

  const int gemm_grid = (T_ * B_ / 128) * (G_ / 128);  // 16384

  if (gx32) {
    k_gemm<I_, true><<<gemm_grid, 256, 0, stream>>>(xbt, wih0b, bih0, bhh0, gx);
    k_scan<true, false><<<256, 256, 0, stream>>>(gx, whh0b, hb1, nullptr, flags0, 0);
    k_gemm<H_, true><<<gemm_grid, 256, 0, stream>>>(hb1, wih1b, bih1, bhh1, gx);
    k_scan<true, true><<<256, 256, 0, stream>>>(gx, whh1b, ring, out, flags1, 1);
  } else {
    k_gemm<I_, false><<<gemm_grid, 256, 0, stream>>>(xbt, wih0b, bih0, bhh0, gx);
    k_scan<false, false><<<256, 256, 0, stream>>>(gx, whh0b, hb1, nullptr, flags0, 0);
    k_gemm<H_, false><<<gemm_grid, 256, 0, stream>>>(hb1, wih1b, bih1, bhh1, gx);
    k_scan<false, true><<<256, 256, 0, stream>>>(gx, whh1b, ring, out, flags1, 1);
  }
}

// Round 8
// 4027.576 us; speedup vs baseline: 6.2966x; 1.0381x over previous
//
#include <hip/hip_runtime.h>
#include <hip/hip_bf16.h>
#include <stdint.h>

// 2-layer LSTM, B=512 T=256 I=128 H=512.  Round 7 design (2nd submit; round-7 bench was
// a broker acquisition timeout, never ran):
//  - Rounds 5/6 failed at ~1e-2 absmax with the sc0-only "L2 fast path" (sc0 alone is
//    CU-scope; stale L1/L2 h reads). Fast path + XCD consensus DELETED. All exchange
//    traffic uses the round-4-proven system-scope sc0 sc1 (LLC) protocol.
//  - Kept from round 5: ring-2 exchange buffer (LLC-resident); layer-0 history and
//    layer-1 fp32 output written with plain cached stores AFTER the flag release
//    (off the per-step critical path; round 4 drained them before every flag).
//  - gx fp32 (bf16 only as ws-too-small fallback; never triggers at this shape).
//  - Flag semantics = round 4: flags memset 0; after step t flag=t+1; poll at step t
//    requires all peers >= t (own slot excluded).

#define B_ 512
#define T_ 256
#define I_ 128
#define H_ 512
#define G_ 2048  // 4H

typedef __attribute__((ext_vector_type(8))) short short8;
typedef __attribute__((ext_vector_type(4))) float f32x4;
typedef unsigned short u16;
typedef unsigned int u32;

__device__ inline u16 f2b(float f) {
  union { __hip_bfloat16 h; u16 u; } cv;
  cv.h = __float2bfloat16(f);
  return cv.u;
}
__device__ inline float b2f(u16 u) {
  union { __hip_bfloat16 h; u16 u; } cv;
  cv.u = u;
  return __bfloat162float(cv.h);
}
__device__ inline float sigm(float x) {
  return __builtin_amdgcn_rcpf(1.0f + __builtin_amdgcn_exp2f(-1.4426950408889634f * x));
}
__device__ inline float tanh_(float x) {
  return 1.0f - 2.0f * __builtin_amdgcn_rcpf(__builtin_amdgcn_exp2f(2.8853900817779268f * x) + 1.0f);
}

// ---- system-scope (LLC) access helpers: per-access sc0 sc1, no cache-wide fences ----
__device__ inline short8 ld_h128_coh(const void* p) {
  f32x4 r;
  asm volatile("global_load_dwordx4 %0, %1, off sc0 sc1" : "=v"(r) : "v"(p) : "memory");
  union { f32x4 f; short8 s; } cv;
  cv.f = r;
  return cv.s;
}
__device__ inline u32 ld_dw_coh(const u32* p) {
  u32 r;
  asm volatile("global_load_dword %0, %1, off sc0 sc1\n\ts_waitcnt vmcnt(0)"
               : "=v"(r) : "v"(p) : "memory");
  return r;
}
__device__ inline void st_h16_coh(void* p, u32 v) {
  asm volatile("global_store_short %0, %1, off sc0 sc1" ::"v"(p), "v"(v) : "memory");
}
__device__ inline void st_dw_coh(u32* p, u32 v) {
  asm volatile("global_store_dword %0, %1, off sc0 sc1" ::"v"(p), "v"(v) : "memory");
}

// x [B,T,I] f32 -> xbt [T,B,I] bf16
__global__ __launch_bounds__(256) void k_xcvt(const float* __restrict__ x, u16* __restrict__ xbt) {
  int i = blockIdx.x * 256 + threadIdx.x;  // over T*B*I/4
  int d4 = i & (I_ / 4 - 1);
  int rb = i >> 5;  // t*B + b
  int b = rb & (B_ - 1);
  int t = rb >> 9;
  const float4 v = *(const float4*)(x + ((size_t)b * T_ + t) * I_ + d4 * 4);
  ushort4 o = make_ushort4(f2b(v.x), f2b(v.y), f2b(v.z), f2b(v.w));
  *(ushort4*)(xbt + (size_t)rb * I_ + d4 * 4) = o;
}

__global__ __launch_bounds__(256) void k_cvt_bf16(const float* __restrict__ in, u16* __restrict__ out, int n4) {
  int i = blockIdx.x * 256 + threadIdx.x;
  if (i >= n4) return;
  const float4 v = *(const float4*)(in + (size_t)i * 4);
  ushort4 o = make_ushort4(f2b(v.x), f2b(v.y), f2b(v.z), f2b(v.w));
  *(ushort4*)(out + (size_t)i * 4) = o;
}

// C[M,2048] = A[M,K] @ Bw[2048,K]^T + (bias_a+bias_b); M = T*B rows (t-major).
template <int KDIM, bool GX32>
__global__ __launch_bounds__(256) void k_gemm(const u16* __restrict__ A,
                                              const u16* __restrict__ Bw,
                                              const float* __restrict__ bias_a,
                                              const float* __restrict__ bias_b,
                                              void* __restrict__ C) {
  __shared__ u16 lA[128 * 64];
  __shared__ u16 lB[128 * 64];
  const int nwg = gridDim.x;
  const int per = nwg >> 3;
  const int wg = blockIdx.x;
  const int swz = (wg & 7) * per + (wg >> 3);
  const int bn = swz & 15;
  const int bm = swz >> 4;
  const size_t m0 = (size_t)bm * 128;
  const int n0 = bn * 128;
  const int tid = threadIdx.x;
  const int lane = tid & 63;
  const int wid = tid >> 6;
  const int wm = (wid >> 1) * 64;
  const int wn = (wid & 1) * 64;
  const int l15 = lane & 15;
  const int lq = lane >> 4;

  f32x4 acc[4][4] = {};

  for (int k0 = 0; k0 < KDIM; k0 += 64) {
    __syncthreads();
#pragma unroll
    for (int it = 0; it < 4; ++it) {
      int c = it * 256 + tid;
      int r = c >> 3, s = c & 7;
      int ss = s ^ (r & 7);
      *(float4*)&lA[(r * 8 + ss) * 8] = *(const float4*)&A[(m0 + r) * KDIM + k0 + s * 8];
      *(float4*)&lB[(r * 8 + ss) * 8] = *(const float4*)&Bw[(size_t)(n0 + r) * KDIM + k0 + s * 8];
    }
    __syncthreads();
#pragma unroll
    for (int kk = 0; kk < 2; ++kk) {
      short8 af[4], bfm[4];
#pragma unroll
      for (int mi = 0; mi < 4; ++mi) {
        int r = wm + mi * 16 + l15;
        int s = kk * 4 + lq;
        af[mi] = *(const short8*)&lA[(r * 8 + (s ^ (r & 7))) * 8];
      }
#pragma unroll
      for (int ni = 0; ni < 4; ++ni) {
        int r = wn + ni * 16 + l15;
        int s = kk * 4 + lq;
        bfm[ni] = *(const short8*)&lB[(r * 8 + (s ^ (r & 7))) * 8];
      }
#pragma unroll
      for (int mi = 0; mi < 4; ++mi)
#pragma unroll
        for (int ni = 0; ni < 4; ++ni)
          acc[mi][ni] = __builtin_amdgcn_mfma_f32_16x16x32_bf16(af[mi], bfm[ni], acc[mi][ni], 0, 0, 0);
    }
  }

#pragma unroll
  for (int ni = 0; ni < 4; ++ni) {
    int col = n0 + wn + ni * 16 + l15;
    float bs = bias_a[col] + bias_b[col];
#pragma unroll
    for (int mi = 0; mi < 4; ++mi) {
#pragma unroll
      for (int r = 0; r < 4; ++r) {
        size_t row = m0 + wm + mi * 16 + lq * 4 + r;
        float v = acc[mi][ni][r] + bs;
        if (GX32) ((float*)C)[row * G_ + col] = v;
        else ((u16*)C)[row * G_ + col] = f2b(v);
      }
    }
  }
}

// Persistent scan. 256 blocks = 8 batch groups (Bi=blk&7, 64 rows) x 32 gate-col slices
// (j=blk>>3, 64 gate rows = 16 h cols). W slice in 64KB swizzled LDS; h exchanged via
// ring-2 at LLC scope (sc0 sc1); per-block flag slot (monotonic completed-step counter).
// hist/fpout written with plain cached stores AFTER the flag release (off critical path).
template <bool GX32>
__global__ __launch_bounds__(256, 1) void k_scan(const void* __restrict__ gx,  // [T,B,2048]
                                                 const u16* __restrict__ Whh,  // [2048,512] bf16
                                                 u16* __restrict__ ring,       // 2*B*H bf16
                                                 u16* __restrict__ hist,       // [T,B,H] bf16 or null
                                                 float* __restrict__ fpout,    // [B,T,H] f32 or null
                                                 u32* __restrict__ flags) {    // [8 groups][32 slots]
  __shared__ u16 lW[64 * 512];  // 64KB, swizzled

  const int blk = blockIdx.x;
  const int Bi = blk & 7;
  const int j = blk >> 3;
  const int tid = threadIdx.x;
  const int lane = tid & 63;
  const int wid = tid >> 6;
  const int l15 = lane & 15;
  const int lq = lane >> 4;

  // Stage W_hh slice once: local row r = g*16+i  <->  global gate row g*512 + j*16 + i
  for (int c = tid; c < 64 * 64; c += 256) {
    int r = c >> 6, s = c & 63;
    int gr = (r >> 4) * 512 + j * 16 + (r & 15);
    *(float4*)&lW[r * 512 + (s ^ (r & 7)) * 8] = *(const float4*)&Whh[(size_t)gr * H_ + s * 8];
  }
  __syncthreads();

  const int arow = Bi * 64 + wid * 16 + l15;      // this lane's A-fragment h row
  const int brow0 = Bi * 64 + wid * 16 + lq * 4;  // C rows (+r)
  const int colj = j * 16 + l15;
  u32* myflags = flags + Bi * 32;
  const int selfslot = ((lane & 31) == j) ? 1 : 0;
  float cst[4] = {0.f, 0.f, 0.f, 0.f};

  for (int t = 0; t < T_; ++t) {
    // gx loads issued early (plain cached); latency overlaps the producer wait
    float gxv[4][4];
    if (GX32) {
      const float* gp = (const float*)gx + ((size_t)t * B_ + brow0) * G_ + colj;
#pragma unroll
      for (int g = 0; g < 4; ++g)
#pragma unroll
        for (int r = 0; r < 4; ++r) gxv[g][r] = gp[(size_t)r * G_ + g * H_];
    } else {
      const u16* gp = (const u16*)gx + ((size_t)t * B_ + brow0) * G_ + colj;
#pragma unroll
      for (int g = 0; g < 4; ++g)
#pragma unroll
        for (int r = 0; r < 4; ++r) gxv[g][r] = b2f(gp[(size_t)r * G_ + g * H_]);
    }

    f32x4 acc[4] = {};

    if (t > 0) {
      // wait for all 32 producers of this batch group to have finished step t-1
      // (own slot excluded: own stores drained before our step-(t-1) flag)
      u32 guard = 0;
      for (;;) {
        u32 v = ld_dw_coh(&myflags[lane & 31]);
        if (__all(selfslot | (v >= (u32)t))) break;
        if (++guard > (1u << 20)) break;  // bounded: wrong answer instead of hang
      }
      const u16* hs = ring + (size_t)((t - 1) & 1) * B_ * H_ + (size_t)arow * H_;
      short8 af[16];
#pragma unroll
      for (int kk = 0; kk < 16; ++kk) af[kk] = ld_h128_coh(hs + (kk * 4 + lq) * 8);
      asm volatile("s_waitcnt vmcnt(0)" ::: "memory");
      __builtin_amdgcn_sched_barrier(0);
#pragma unroll
      for (int kk = 0; kk < 16; ++kk) {
        int s = kk * 4 + lq;
#pragma unroll
        for (int g = 0; g < 4; ++g) {
          int br = g * 16 + l15;
          short8 bw = *(const short8*)&lW[br * 512 + (s ^ (br & 7)) * 8];
          acc[g] = __builtin_amdgcn_mfma_f32_16x16x32_bf16(af[kk], bw, acc[g], 0, 0, 0);
        }
      }
    }

    u16* hw = ring + (size_t)(t & 1) * B_ * H_;
    u16 hh[4];
    float hv[4];
#pragma unroll
    for (int r = 0; r < 4; ++r) {
      float gi = sigm(acc[0][r] + gxv[0][r]);
      float gf = sigm(acc[1][r] + gxv[1][r]);
      float gg = tanh_(acc[2][r] + gxv[2][r]);
      float go = sigm(acc[3][r] + gxv[3][r]);
      float cn = gf * cst[r] + gi * gg;
      cst[r] = cn;
      float hn = go * tanh_(cn);
      hv[r] = hn;
      hh[r] = f2b(hn);
      st_h16_coh(&hw[(size_t)(brow0 + r) * H_ + colj], (u32)hh[r]);
    }
    asm volatile("s_waitcnt vmcnt(0)" ::: "memory");  // ring stores at LLC
    __syncthreads();                                  // all waves of block drained
    if (tid == 0) st_dw_coh(&myflags[j], (u32)(t + 1));

    // off-critical-path outputs (plain cached stores, after flag release)
    if (hist) {
#pragma unroll
      for (int r = 0; r < 4; ++r) hist[((size_t)t * B_ + brow0 + r) * H_ + colj] = hh[r];
    }
    if (fpout) {
#pragma unroll
      for (int r = 0; r < 4; ++r) fpout[((size_t)(brow0 + r) * T_ + t) * H_ + colj] = hv[r];
    }
  }
}

extern "C" void kernel_launch(void* const* d_in, const int* in_sizes, int n_in,
                              void* d_out, int out_size, void* d_ws, size_t ws_size,
                              hipStream_t stream) {
  if (n_in < 9) return;
  const float* x    = (const float*)d_in[0];
  const float* Wih0 = (const float*)d_in[1];
  const float* Whh0 = (const float*)d_in[2];
  const float* bih0 = (const float*)d_in[3];
  const float* bhh0 = (const float*)d_in[4];
  const float* Wih1 = (const float*)d_in[5];
  const float* Whh1 = (const float*)d_in[6];
  const float* bih1 = (const float*)d_in[7];
  const float* bhh1 = (const float*)d_in[8];
  float* out = (float*)d_out;

  const size_t SZ_GX32 = (size_t)T_ * B_ * G_ * 4;
  const size_t SZ_GX16 = (size_t)T_ * B_ * G_ * 2;
  const size_t SZ_XBT  = (size_t)T_ * B_ * I_ * 2;
  const size_t SZ_HB1  = (size_t)T_ * B_ * H_ * 2;
  const size_t SZ_RING = (size_t)2 * B_ * H_ * 2;
  const size_t SZ_WIH0 = (size_t)G_ * I_ * 2;
  const size_t SZ_WHH  = (size_t)G_ * H_ * 2;
  const size_t SZ_SYNC = (size_t)2 * 8 * 32 * sizeof(u32);  // flags0, flags1
  const size_t others = SZ_XBT + SZ_HB1 + SZ_RING + SZ_WIH0 + 3 * SZ_WHH + SZ_SYNC + 4096;

  bool gx32 = ws_size >= SZ_GX32 + others;  // fp32 gx (round-4-proven numerics)
  if (!gx32 && ws_size < SZ_GX16 + others) return;  // ws too small: fail loudly

  uint8_t* p = (uint8_t*)d_ws;
  void* gx   = (void*)p;  p += gx32 ? SZ_GX32 : SZ_GX16;
  u16* xbt   = (u16*)p;   p += SZ_XBT;
  u16* hb1   = (u16*)p;   p += SZ_HB1;
  u16* ring  = (u16*)p;   p += SZ_RING;
  u16* wih0b = (u16*)p;   p += SZ_WIH0;
  u16* whh0b = (u16*)p;   p += SZ_WHH;
  u16* wih1b = (u16*)p;   p += SZ_WHH;
  u16* whh1b = (u16*)p;   p += SZ_WHH;
  u32* sync   = (u32*)p;
  u32* flags0 = sync;
  u32* flags1 = sync + 8 * 32;

  k_xcvt<<<(T_ * B_ * I_ / 4) / 256, 256, 0, stream>>>(x, xbt);
  k_cvt_bf16<<<(G_ * I_ / 4) / 256, 256, 0, stream>>>(Wih0, wih0b, G_ * I_ / 4);
  k_cvt_bf16<<<(G_ * H_ / 4) / 256, 256, 0, stream>>>(Whh0, whh0b, G_ * H_ / 4);
  k_cvt_bf16<<<(G_ * H_ / 4) / 256, 256, 0, stream>>>(Wih1, wih1b, G_ * H_ / 4);
  k_cvt_bf16<<<(G_ * H_ / 4) / 256, 256, 0, stream>>>(Whh1, whh1b, G_ * H_ / 4);
  hipMemsetAsync(sync, 0, SZ_SYNC, stream);

  const int gemm_grid = (T_ * B_ / 128) * (G_ / 128);  // 16384

  if (gx32) {
    k_gemm<I_, true><<<gemm_grid, 256, 0, stream>>>(xbt, wih0b, bih0, bhh0, gx);
    k_scan<true><<<256, 256, 0, stream>>>(gx, whh0b, ring, hb1, nullptr, flags0);
    k_gemm<H_, true><<<gemm_grid, 256, 0, stream>>>(hb1, wih1b, bih1, bhh1, gx);
    k_scan<true><<<256, 256, 0, stream>>>(gx, whh1b, ring, nullptr, out, flags1);
  } else {
    k_gemm<I_, false><<<gemm_grid, 256, 0, stream>>>(xbt, wih0b, bih0, bhh0, gx);
    k_scan<false><<<256, 256, 0, stream>>>(gx, whh0b, ring, hb1, nullptr, flags0);
    k_gemm<H_, false><<<gemm_grid, 256, 0, stream>>>(hb1, wih1b, bih1, bhh1, gx);
    k_scan<false><<<256, 256, 0, stream>>>(gx, whh1b, ring, nullptr, out, flags1);
  }
}